// Round 5
// baseline (637.591 us; speedup 1.0000x reference)
//
#include <hip/hip_runtime.h>
#include <math.h>

#define BB 64
#define SS 2048
#define DD 512
#define CH 16
#define ROWS (SS/CH)        // 128 rows per chunk
#define WROWS (ROWS/4)      // 32 rows per wave
#define RPI 4               // rows per wave-iteration (batched online softmax)
#define ITERS (WROWS/RPI)   // 8 iterations per wave

// ---------------- kernel 1: w[b,d] = (concat(c1,q)[b,:] . W_d2d[d,:] + b_d[d]) * W_1d[d]
// Also zeroes the per-batch completion tickets used by k_pass's fused combine.
__global__ __launch_bounds__(128) void k_w(
    const float* __restrict__ c1, const float* __restrict__ q,
    const float* __restrict__ Wd, const float* __restrict__ bd,
    const float* __restrict__ W1, float* __restrict__ w,
    int* __restrict__ ticket)
{
    __shared__ float conc[2*DD];
    const int b = blockIdx.y;
    const int t = threadIdx.x;
    if (blockIdx.x == 0 && t == 0) ticket[b] = 0;
    for (int i = t; i < DD; i += 128) {
        conc[i]      = c1[b*DD + i];
        conc[DD + i] = q[b*DD + i];
    }
    __syncthreads();
    const int d = blockIdx.x * 128 + t;
    const float4* Wr = (const float4*)(Wd + (size_t)d * (2*DD));
    const float4* cc = (const float4*)conc;
    float acc = 0.f;
    #pragma unroll 8
    for (int k = 0; k < (2*DD)/4; ++k) {
        float4 a = Wr[k];
        float4 c = cc[k];
        acc += a.x*c.x + a.y*c.y + a.z*c.z + a.w*c.w;
    }
    w[b*DD + d] = (acc + bd[d]) * W1[d];
}

// ---------------- kernel 2: online-softmax partial over a chunk of 128 rows
// Main loop identical to the 405-us R2 version (4 waves/block, 4 rows per
// iteration, batched butterflies, group prefetch). New: fused split-K-style
// epilogue — the last chunk-block of each batch (device-scope ticket) merges
// the 16 partials and writes the final output, eliminating the k_comb launch.
__global__ __launch_bounds__(256) void k_pass(
    const float* __restrict__ cw, const float* __restrict__ w,
    float* __restrict__ pm, float* __restrict__ pl, float* __restrict__ pacc,
    int* __restrict__ ticket, float* __restrict__ out)
{
    const int blk  = blockIdx.x;
    const int b    = blk >> 4;        // /CH
    const int ch   = blk & (CH - 1);
    const int tid  = threadIdx.x;
    const int wave = tid >> 6;
    const int lane = tid & 63;

    // per-lane slice of w: d = 4*lane .. +3  and  256 + 4*lane .. +3
    const float4* wb = (const float4*)(w + b*DD);
    const float4 w0 = wb[lane];
    const float4 w1 = wb[64 + lane];

    // wave's contiguous 32-row strip
    const float* rb = cw + ((size_t)b*SS + (size_t)ch*ROWS + (size_t)wave*WROWS) * DD;

    // load first group of 4 rows
    float4 c0[RPI], c1v[RPI];
    #pragma unroll
    for (int r = 0; r < RPI; ++r) {
        const float4* p = (const float4*)(rb + (size_t)r * DD);
        c0[r]  = p[lane];
        c1v[r] = p[64 + lane];
    }

    float m = -INFINITY, l = 0.f;
    float4 a0 = make_float4(0,0,0,0), a1 = make_float4(0,0,0,0);

    #pragma unroll 2
    for (int i = 0; i < ITERS; ++i) {
        // prefetch next group (clamped on last iter: re-reads hot lines, cheap)
        const int nx = (i + 1 < ITERS) ? (i + 1) : i;
        const float* nbase = rb + (size_t)nx * RPI * DD;
        float4 n0[RPI], n1[RPI];
        #pragma unroll
        for (int r = 0; r < RPI; ++r) {
            const float4* p = (const float4*)(nbase + (size_t)r * DD);
            n0[r] = p[lane];
            n1[r] = p[64 + lane];
        }

        // 4 per-lane partial dots
        float d_[RPI];
        #pragma unroll
        for (int r = 0; r < RPI; ++r) {
            d_[r] = c0[r].x*w0.x + c0[r].y*w0.y + c0[r].z*w0.z + c0[r].w*w0.w
                  + c1v[r].x*w1.x + c1v[r].y*w1.y + c1v[r].z*w1.z + c1v[r].w*w1.w;
        }
        // 4 independent butterflies — pipelined through the 6 steps
        #pragma unroll
        for (int off = 32; off; off >>= 1) {
            #pragma unroll
            for (int r = 0; r < RPI; ++r) d_[r] += __shfl_xor(d_[r], off, 64);
        }

        // batched online-softmax update (one rescale per 4 rows)
        float mn = fmaxf(fmaxf(d_[0], d_[1]), fmaxf(d_[2], d_[3]));
        mn = fmaxf(mn, m);
        const float alpha = __expf(m - mn);   // first iter: expf(-inf) = 0
        m = mn;
        float pr[RPI];
        #pragma unroll
        for (int r = 0; r < RPI; ++r) pr[r] = __expf(d_[r] - m);
        l = l*alpha + (pr[0] + pr[1] + pr[2] + pr[3]);
        a0.x *= alpha; a0.y *= alpha; a0.z *= alpha; a0.w *= alpha;
        a1.x *= alpha; a1.y *= alpha; a1.z *= alpha; a1.w *= alpha;
        #pragma unroll
        for (int r = 0; r < RPI; ++r) {
            a0.x += pr[r]*c0[r].x;  a0.y += pr[r]*c0[r].y;
            a0.z += pr[r]*c0[r].z;  a0.w += pr[r]*c0[r].w;
            a1.x += pr[r]*c1v[r].x; a1.y += pr[r]*c1v[r].y;
            a1.z += pr[r]*c1v[r].z; a1.w += pr[r]*c1v[r].w;
        }

        // rotate buffers
        #pragma unroll
        for (int r = 0; r < RPI; ++r) { c0[r] = n0[r]; c1v[r] = n1[r]; }
    }

    // combine 4 waves within the block
    __shared__ float lm[4], ll[4];
    __shared__ float lacc[4][DD];
    if (lane == 0) lm[wave] = m;
    __syncthreads();
    const float M4 = fmaxf(fmaxf(lm[0], lm[1]), fmaxf(lm[2], lm[3]));
    const float beta = __expf(m - M4);
    float4* lw = (float4*)lacc[wave];
    lw[lane]      = make_float4(a0.x*beta, a0.y*beta, a0.z*beta, a0.w*beta);
    lw[64 + lane] = make_float4(a1.x*beta, a1.y*beta, a1.z*beta, a1.w*beta);
    if (lane == 0) ll[wave] = l * beta;
    __syncthreads();
    const float s0 = lacc[0][tid]     + lacc[1][tid]     + lacc[2][tid]     + lacc[3][tid];
    const float s1 = lacc[0][tid+256] + lacc[1][tid+256] + lacc[2][tid+256] + lacc[3][tid+256];
    pacc[(size_t)blk*DD + tid]       = s0;
    pacc[(size_t)blk*DD + tid + 256] = s1;
    if (tid == 0) {
        pm[blk] = M4;
        pl[blk] = ll[0] + ll[1] + ll[2] + ll[3];
    }

    // ---- fused combine: last chunk-block of this batch merges the partials
    __threadfence();                       // release: partials visible device-wide
    __shared__ int lastFlag;
    if (tid == 0) {
        const int old = atomicAdd(&ticket[b], 1);   // device-scope by default
        lastFlag = (old == CH - 1);
    }
    __syncthreads();
    if (!lastFlag) return;
    __threadfence();                       // acquire

    float M = -INFINITY;
    float mp[CH];
    #pragma unroll
    for (int p = 0; p < CH; ++p) {
        mp[p] = __hip_atomic_load(&pm[b*CH + p], __ATOMIC_RELAXED, __HIP_MEMORY_SCOPE_AGENT);
        M = fmaxf(M, mp[p]);
    }
    float L = 0.f, sx = 0.f, sy = 0.f;
    #pragma unroll
    for (int p = 0; p < CH; ++p) {
        const float lp = __hip_atomic_load(&pl[b*CH + p], __ATOMIC_RELAXED, __HIP_MEMORY_SCOPE_AGENT);
        const float sc = __expf(mp[p] - M);
        L += lp * sc;
        const float2 v = ((const float2*)(pacc + (size_t)(b*CH + p)*DD))[tid];
        sx += sc * v.x;
        sy += sc * v.y;
    }
    const float inv = 1.f / L;
    ((float2*)(out + b*DD))[tid] = make_float2(sx*inv, sy*inv);
}

extern "C" void kernel_launch(void* const* d_in, const int* in_sizes, int n_in,
                              void* d_out, int out_size, void* d_ws, size_t ws_size,
                              hipStream_t stream)
{
    const float* c1 = (const float*)d_in[0];   // c_i_1 [B,D]
    const float* q  = (const float*)d_in[1];   // q     [B,D]
    const float* cw = (const float*)d_in[2];   // cw_s  [B,S,D]
    const float* Wd = (const float*)d_in[3];   // W_d2d [D,2D]
    const float* bd = (const float*)d_in[4];   // b_d   [D]
    const float* W1 = (const float*)d_in[5];   // W_1d  [1,D]
    // d_in[6] = b_1: constant logit shift -> cancels in softmax, unused.

    float* out  = (float*)d_out;
    float* ws   = (float*)d_ws;
    float* w    = ws;                    // B*D          = 32768 floats
    float* pm   = w  + BB*DD;            // B*CH         = 1024
    float* pl   = pm + BB*CH;            // B*CH         = 1024
    float* pacc = pl + BB*CH;            // B*CH*D       = 524288
    int* ticket = (int*)(pacc + (size_t)BB*CH*DD);  // B ints

    k_w   <<<dim3(DD/128, BB), 128, 0, stream>>>(c1, q, Wd, bd, W1, w, ticket);
    k_pass<<<BB*CH,            256, 0, stream>>>(cw, w, pm, pl, pacc, ticket, out);
}

// Round 6
// 486.916 us; speedup vs baseline: 1.3094x; 1.3094x over previous
//
#include <hip/hip_runtime.h>
#include <math.h>

#define BB 64
#define SS 2048
#define DD 512
#define CH 16
#define ROWS (SS/CH)        // 128 rows per chunk
#define WROWS (ROWS/4)      // 32 rows per wave
#define RPI 4               // rows per wave-iteration
#define ITERS (WROWS/RPI)   // 8 groups per wave

// ---------------- kernel 1: w[b,d] = (concat(c1,q)[b,:] . W_d2d[d,:] + b_d[d]) * W_1d[d]
__global__ __launch_bounds__(128) void k_w(
    const float* __restrict__ c1, const float* __restrict__ q,
    const float* __restrict__ Wd, const float* __restrict__ bd,
    const float* __restrict__ W1, float* __restrict__ w)
{
    __shared__ float conc[2*DD];
    const int b = blockIdx.y;
    const int t = threadIdx.x;
    for (int i = t; i < DD; i += 128) {
        conc[i]      = c1[b*DD + i];
        conc[DD + i] = q[b*DD + i];
    }
    __syncthreads();
    const int d = blockIdx.x * 128 + t;
    const float4* Wr = (const float4*)(Wd + (size_t)d * (2*DD));
    const float4* cc = (const float4*)conc;
    float acc = 0.f;
    #pragma unroll 8
    for (int k = 0; k < (2*DD)/4; ++k) {
        float4 a = Wr[k];
        float4 c = cc[k];
        acc += a.x*c.x + a.y*c.y + a.z*c.z + a.w*c.w;
    }
    w[b*DD + d] = (acc + bd[d]) * W1[d];
}

// ---------------- kernel 2: online-softmax partial over a chunk of 128 rows
// R5 evidence: compiler sank the prefetch (VGPR=44, 373 GB/s, VALUBusy 1.8%
// -> fully latency-serialized). Fix: manual even/odd double buffer (A/B),
// loads pinned ahead of the other group's compute with sched_barrier(0),
// launch_bounds(256,4) caps VGPR at 128 (= grid's 4 blocks/CU exactly).
// While STEP(X) computes, the other group's 8 dwordx4 loads are in flight.

#define LOADG(DST0, DST1, g)                                                  \
    {   const float* nb_ = rb + (size_t)(g) * RPI * DD;                       \
        _Pragma("unroll")                                                     \
        for (int r = 0; r < RPI; ++r) {                                       \
            const float4* p_ = (const float4*)(nb_ + (size_t)r * DD);         \
            DST0[r] = p_[lane];                                               \
            DST1[r] = p_[64 + lane];                                          \
        } }

#define STEP(C0, C1)                                                          \
    {   float d_[RPI];                                                        \
        _Pragma("unroll")                                                     \
        for (int r = 0; r < RPI; ++r)                                         \
            d_[r] = C0[r].x*w0.x + C0[r].y*w0.y + C0[r].z*w0.z + C0[r].w*w0.w \
                  + C1[r].x*w1.x + C1[r].y*w1.y + C1[r].z*w1.z + C1[r].w*w1.w;\
        _Pragma("unroll")                                                     \
        for (int off = 32; off; off >>= 1) {                                  \
            _Pragma("unroll")                                                 \
            for (int r = 0; r < RPI; ++r) d_[r] += __shfl_xor(d_[r], off, 64);\
        }                                                                     \
        float mn = fmaxf(fmaxf(d_[0], d_[1]), fmaxf(d_[2], d_[3]));           \
        mn = fmaxf(mn, m);                                                    \
        const float alpha = __expf(m - mn);                                   \
        m = mn;                                                               \
        float pr[RPI];                                                        \
        _Pragma("unroll")                                                     \
        for (int r = 0; r < RPI; ++r) pr[r] = __expf(d_[r] - m);              \
        l = l*alpha + (pr[0] + pr[1] + pr[2] + pr[3]);                        \
        a0.x *= alpha; a0.y *= alpha; a0.z *= alpha; a0.w *= alpha;           \
        a1.x *= alpha; a1.y *= alpha; a1.z *= alpha; a1.w *= alpha;           \
        _Pragma("unroll")                                                     \
        for (int r = 0; r < RPI; ++r) {                                       \
            a0.x += pr[r]*C0[r].x; a0.y += pr[r]*C0[r].y;                     \
            a0.z += pr[r]*C0[r].z; a0.w += pr[r]*C0[r].w;                     \
            a1.x += pr[r]*C1[r].x; a1.y += pr[r]*C1[r].y;                     \
            a1.z += pr[r]*C1[r].z; a1.w += pr[r]*C1[r].w;                     \
        } }

__global__ __launch_bounds__(256, 4) void k_pass(
    const float* __restrict__ cw, const float* __restrict__ w,
    float* __restrict__ pm, float* __restrict__ pl, float* __restrict__ pacc)
{
    const int blk  = blockIdx.x;
    const int b    = blk >> 4;        // /CH
    const int ch   = blk & (CH - 1);
    const int tid  = threadIdx.x;
    const int wave = tid >> 6;
    const int lane = tid & 63;

    // per-lane slice of w: d = 4*lane .. +3  and  256 + 4*lane .. +3
    const float4* wb = (const float4*)(w + b*DD);
    const float4 w0 = wb[lane];
    const float4 w1 = wb[64 + lane];

    // wave's contiguous 32-row strip
    const float* rb = cw + ((size_t)b*SS + (size_t)ch*ROWS + (size_t)wave*WROWS) * DD;

    float4 A0[RPI], A1[RPI], B0[RPI], B1[RPI];
    LOADG(A0, A1, 0);

    float m = -INFINITY, l = 0.f;
    float4 a0 = make_float4(0,0,0,0), a1 = make_float4(0,0,0,0);

    // ITERS = 8 -> 4 fully-unrolled pairs; all buffer indices compile-time.
    #pragma unroll
    for (int i = 0; i < ITERS; i += 2) {
        LOADG(B0, B1, i + 1);                 // prefetch group i+1
        __builtin_amdgcn_sched_barrier(0);    // pin: loads stay issued here
        STEP(A0, A1);                         // compute group i
        if (i + 2 < ITERS) {
            LOADG(A0, A1, i + 2);             // prefetch group i+2
        }
        __builtin_amdgcn_sched_barrier(0);
        STEP(B0, B1);                         // compute group i+1
    }

    // combine 4 waves within the block
    __shared__ float lm[4], ll[4];
    __shared__ float lacc[4][DD];
    if (lane == 0) lm[wave] = m;
    __syncthreads();
    const float M = fmaxf(fmaxf(lm[0], lm[1]), fmaxf(lm[2], lm[3]));
    const float beta = __expf(m - M);
    float4* lw = (float4*)lacc[wave];
    lw[lane]      = make_float4(a0.x*beta, a0.y*beta, a0.z*beta, a0.w*beta);
    lw[64 + lane] = make_float4(a1.x*beta, a1.y*beta, a1.z*beta, a1.w*beta);
    if (lane == 0) ll[wave] = l * beta;
    __syncthreads();
    const float s0 = lacc[0][tid]     + lacc[1][tid]     + lacc[2][tid]     + lacc[3][tid];
    const float s1 = lacc[0][tid+256] + lacc[1][tid+256] + lacc[2][tid+256] + lacc[3][tid+256];
    pacc[(size_t)blk*DD + tid]       = s0;
    pacc[(size_t)blk*DD + tid + 256] = s1;
    if (tid == 0) {
        pm[blk] = M;
        pl[blk] = ll[0] + ll[1] + ll[2] + ll[3];
    }
}

// ---------------- kernel 3: merge 16 chunk-partials per batch (float2-vectorized)
__global__ __launch_bounds__(256) void k_comb(
    const float* __restrict__ pm, const float* __restrict__ pl,
    const float* __restrict__ pacc, float* __restrict__ out)
{
    const int b = blockIdx.x;
    const int tid = threadIdx.x;
    float M = -INFINITY;
    #pragma unroll
    for (int p = 0; p < CH; ++p) M = fmaxf(M, pm[b*CH + p]);
    float L = 0.f;
    float sx = 0.f, sy = 0.f;
    #pragma unroll
    for (int p = 0; p < CH; ++p) {
        const float sc = __expf(pm[b*CH + p] - M);
        L += pl[b*CH + p] * sc;
        const float2 v = ((const float2*)(pacc + (size_t)(b*CH + p)*DD))[tid];
        sx += sc * v.x;
        sy += sc * v.y;
    }
    const float inv = 1.f / L;
    ((float2*)(out + b*DD))[tid] = make_float2(sx*inv, sy*inv);
}

extern "C" void kernel_launch(void* const* d_in, const int* in_sizes, int n_in,
                              void* d_out, int out_size, void* d_ws, size_t ws_size,
                              hipStream_t stream)
{
    const float* c1 = (const float*)d_in[0];   // c_i_1 [B,D]
    const float* q  = (const float*)d_in[1];   // q     [B,D]
    const float* cw = (const float*)d_in[2];   // cw_s  [B,S,D]
    const float* Wd = (const float*)d_in[3];   // W_d2d [D,2D]
    const float* bd = (const float*)d_in[4];   // b_d   [D]
    const float* W1 = (const float*)d_in[5];   // W_1d  [1,D]
    // d_in[6] = b_1: constant logit shift -> cancels in softmax, unused.

    float* out  = (float*)d_out;
    float* ws   = (float*)d_ws;
    float* w    = ws;                    // B*D          = 32768 floats
    float* pm   = w  + BB*DD;            // B*CH         = 1024
    float* pl   = pm + BB*CH;            // B*CH         = 1024
    float* pacc = pl + BB*CH;            // B*CH*D       = 524288

    k_w   <<<dim3(DD/128, BB), 128, 0, stream>>>(c1, q, Wd, bd, W1, w);
    k_pass<<<BB*CH,            256, 0, stream>>>(cw, w, pm, pl, pacc);
    k_comb<<<BB,               256, 0, stream>>>(pm, pl, pacc, out);
}

// Round 7
// 485.482 us; speedup vs baseline: 1.3133x; 1.0030x over previous
//
#include <hip/hip_runtime.h>
#include <math.h>

#define BB 64
#define SS 2048
#define DD 512
#define CH 16
#define ROWS (SS/CH)        // 128 rows per chunk
#define WROWS (ROWS/4)      // 32 rows per wave
#define RPI 4               // rows per wave-iteration
#define ITERS (WROWS/RPI)   // 8 groups per wave

// ---------------- kernel 1: w[b,d] = (concat(c1,q)[b,:] . W_d2d[d,:] + b_d[d]) * W_1d[d]
__global__ __launch_bounds__(128) void k_w(
    const float* __restrict__ c1, const float* __restrict__ q,
    const float* __restrict__ Wd, const float* __restrict__ bd,
    const float* __restrict__ W1, float* __restrict__ w)
{
    __shared__ float conc[2*DD];
    const int b = blockIdx.y;
    const int t = threadIdx.x;
    for (int i = t; i < DD; i += 128) {
        conc[i]      = c1[b*DD + i];
        conc[DD + i] = q[b*DD + i];
    }
    __syncthreads();
    const int d = blockIdx.x * 128 + t;
    const float4* Wr = (const float4*)(Wd + (size_t)d * (2*DD));
    const float4* cc = (const float4*)conc;
    float acc = 0.f;
    #pragma unroll 8
    for (int k = 0; k < (2*DD)/4; ++k) {
        float4 a = Wr[k];
        float4 c = cc[k];
        acc += a.x*c.x + a.y*c.y + a.z*c.z + a.w*c.w;
    }
    w[b*DD + d] = (acc + bd[d]) * W1[d];
}

// ---------------- kernel 2: online-softmax partial over a chunk of 128 rows
// R6 evidence: pipeline works (FETCH 253 MB, 2.7 TB/s) but backend shrank
// allocation to the 64-VGPR bucket and spilled the double buffers to scratch
// (WRITE_SIZE 244 MB = ~930 B/thread of spill round-trip). Live set is ~100
// VGPR; __launch_bounds__'s 2nd arg only sets a MINIMUM waves/EU, so the
// occupancy heuristic still spilled. Fix: pin waves/EU to exactly 4
// (amdgpu_waves_per_eu(4,4)) -> VGPR budget exactly 128, no shrink incentive.
// Grid is 4 blocks/CU = 16 waves/CU, so pinning costs zero occupancy.

#define LOADG(DST0, DST1, g)                                                  \
    {   const float* nb_ = rb + (size_t)(g) * RPI * DD;                       \
        _Pragma("unroll")                                                     \
        for (int r = 0; r < RPI; ++r) {                                       \
            const float4* p_ = (const float4*)(nb_ + (size_t)r * DD);         \
            DST0[r] = p_[lane];                                               \
            DST1[r] = p_[64 + lane];                                          \
        } }

#define STEP(C0, C1)                                                          \
    {   float d_[RPI];                                                        \
        _Pragma("unroll")                                                     \
        for (int r = 0; r < RPI; ++r)                                         \
            d_[r] = C0[r].x*w0.x + C0[r].y*w0.y + C0[r].z*w0.z + C0[r].w*w0.w \
                  + C1[r].x*w1.x + C1[r].y*w1.y + C1[r].z*w1.z + C1[r].w*w1.w;\
        _Pragma("unroll")                                                     \
        for (int off = 32; off; off >>= 1) {                                  \
            _Pragma("unroll")                                                 \
            for (int r = 0; r < RPI; ++r) d_[r] += __shfl_xor(d_[r], off, 64);\
        }                                                                     \
        float mn = fmaxf(fmaxf(d_[0], d_[1]), fmaxf(d_[2], d_[3]));           \
        mn = fmaxf(mn, m);                                                    \
        const float alpha = __expf(m - mn);                                   \
        m = mn;                                                               \
        float pr[RPI];                                                        \
        _Pragma("unroll")                                                     \
        for (int r = 0; r < RPI; ++r) pr[r] = __expf(d_[r] - m);              \
        l = l*alpha + (pr[0] + pr[1] + pr[2] + pr[3]);                        \
        a0.x *= alpha; a0.y *= alpha; a0.z *= alpha; a0.w *= alpha;           \
        a1.x *= alpha; a1.y *= alpha; a1.z *= alpha; a1.w *= alpha;           \
        _Pragma("unroll")                                                     \
        for (int r = 0; r < RPI; ++r) {                                       \
            a0.x += pr[r]*C0[r].x; a0.y += pr[r]*C0[r].y;                     \
            a0.z += pr[r]*C0[r].z; a0.w += pr[r]*C0[r].w;                     \
            a1.x += pr[r]*C1[r].x; a1.y += pr[r]*C1[r].y;                     \
            a1.z += pr[r]*C1[r].z; a1.w += pr[r]*C1[r].w;                     \
        } }

__attribute__((amdgpu_waves_per_eu(4, 4)))
__global__ __launch_bounds__(256) void k_pass(
    const float* __restrict__ cw, const float* __restrict__ w,
    float* __restrict__ pm, float* __restrict__ pl, float* __restrict__ pacc)
{
    const int blk  = blockIdx.x;
    const int b    = blk >> 4;        // /CH
    const int ch   = blk & (CH - 1);
    const int tid  = threadIdx.x;
    const int wave = tid >> 6;
    const int lane = tid & 63;

    // per-lane slice of w: d = 4*lane .. +3  and  256 + 4*lane .. +3
    const float4* wb = (const float4*)(w + b*DD);
    const float4 w0 = wb[lane];
    const float4 w1 = wb[64 + lane];

    // wave's contiguous 32-row strip
    const float* rb = cw + ((size_t)b*SS + (size_t)ch*ROWS + (size_t)wave*WROWS) * DD;

    float4 A0[RPI], A1[RPI], B0[RPI], B1[RPI];
    LOADG(A0, A1, 0);

    float m = -INFINITY, l = 0.f;
    float4 a0 = make_float4(0,0,0,0), a1 = make_float4(0,0,0,0);

    // ITERS = 8 -> 4 fully-unrolled pairs; all buffer indices compile-time.
    #pragma unroll
    for (int i = 0; i < ITERS; i += 2) {
        LOADG(B0, B1, i + 1);                 // prefetch group i+1
        __builtin_amdgcn_sched_barrier(0);    // pin: loads stay issued here
        STEP(A0, A1);                         // compute group i
        if (i + 2 < ITERS) {
            LOADG(A0, A1, i + 2);             // prefetch group i+2
        }
        __builtin_amdgcn_sched_barrier(0);
        STEP(B0, B1);                         // compute group i+1
    }

    // combine 4 waves within the block
    __shared__ float lm[4], ll[4];
    __shared__ float lacc[4][DD];
    if (lane == 0) lm[wave] = m;
    __syncthreads();
    const float M = fmaxf(fmaxf(lm[0], lm[1]), fmaxf(lm[2], lm[3]));
    const float beta = __expf(m - M);
    float4* lw = (float4*)lacc[wave];
    lw[lane]      = make_float4(a0.x*beta, a0.y*beta, a0.z*beta, a0.w*beta);
    lw[64 + lane] = make_float4(a1.x*beta, a1.y*beta, a1.z*beta, a1.w*beta);
    if (lane == 0) ll[wave] = l * beta;
    __syncthreads();
    const float s0 = lacc[0][tid]     + lacc[1][tid]     + lacc[2][tid]     + lacc[3][tid];
    const float s1 = lacc[0][tid+256] + lacc[1][tid+256] + lacc[2][tid+256] + lacc[3][tid+256];
    pacc[(size_t)blk*DD + tid]       = s0;
    pacc[(size_t)blk*DD + tid + 256] = s1;
    if (tid == 0) {
        pm[blk] = M;
        pl[blk] = ll[0] + ll[1] + ll[2] + ll[3];
    }
}

// ---------------- kernel 3: merge 16 chunk-partials per batch (float2-vectorized)
__global__ __launch_bounds__(256) void k_comb(
    const float* __restrict__ pm, const float* __restrict__ pl,
    const float* __restrict__ pacc, float* __restrict__ out)
{
    const int b = blockIdx.x;
    const int tid = threadIdx.x;
    float M = -INFINITY;
    #pragma unroll
    for (int p = 0; p < CH; ++p) M = fmaxf(M, pm[b*CH + p]);
    float L = 0.f;
    float sx = 0.f, sy = 0.f;
    #pragma unroll
    for (int p = 0; p < CH; ++p) {
        const float sc = __expf(pm[b*CH + p] - M);
        L += pl[b*CH + p] * sc;
        const float2 v = ((const float2*)(pacc + (size_t)(b*CH + p)*DD))[tid];
        sx += sc * v.x;
        sy += sc * v.y;
    }
    const float inv = 1.f / L;
    ((float2*)(out + b*DD))[tid] = make_float2(sx*inv, sy*inv);
}

extern "C" void kernel_launch(void* const* d_in, const int* in_sizes, int n_in,
                              void* d_out, int out_size, void* d_ws, size_t ws_size,
                              hipStream_t stream)
{
    const float* c1 = (const float*)d_in[0];   // c_i_1 [B,D]
    const float* q  = (const float*)d_in[1];   // q     [B,D]
    const float* cw = (const float*)d_in[2];   // cw_s  [B,S,D]
    const float* Wd = (const float*)d_in[3];   // W_d2d [D,2D]
    const float* bd = (const float*)d_in[4];   // b_d   [D]
    const float* W1 = (const float*)d_in[5];   // W_1d  [1,D]
    // d_in[6] = b_1: constant logit shift -> cancels in softmax, unused.

    float* out  = (float*)d_out;
    float* ws   = (float*)d_ws;
    float* w    = ws;                    // B*D          = 32768 floats
    float* pm   = w  + BB*DD;            // B*CH         = 1024
    float* pl   = pm + BB*CH;            // B*CH         = 1024
    float* pacc = pl + BB*CH;            // B*CH*D       = 524288

    k_w   <<<dim3(DD/128, BB), 128, 0, stream>>>(c1, q, Wd, bd, W1, w);
    k_pass<<<BB*CH,            256, 0, stream>>>(cw, w, pm, pl, pacc);
    k_comb<<<BB,               256, 0, stream>>>(pm, pl, pacc, out);
}

// Round 8
// 403.875 us; speedup vs baseline: 1.5787x; 1.2021x over previous
//
#include <hip/hip_runtime.h>
#include <math.h>

#define BB 64
#define SS 2048
#define DD 512
#define CH 16
#define ROWS (SS/CH)        // 128 rows per chunk
#define WROWS (ROWS/4)      // 32 rows per wave
#define RPI 2               // rows per group (halved: dbuf fits the 64-VGPR bucket)
#define ITERS (WROWS/RPI)   // 16 groups per wave

// ---------------- kernel 1: w[b,d] = (concat(c1,q)[b,:] . W_d2d[d,:] + b_d[d]) * W_1d[d]
__global__ __launch_bounds__(128) void k_w(
    const float* __restrict__ c1, const float* __restrict__ q,
    const float* __restrict__ Wd, const float* __restrict__ bd,
    const float* __restrict__ W1, float* __restrict__ w)
{
    __shared__ float conc[2*DD];
    const int b = blockIdx.y;
    const int t = threadIdx.x;
    for (int i = t; i < DD; i += 128) {
        conc[i]      = c1[b*DD + i];
        conc[DD + i] = q[b*DD + i];
    }
    __syncthreads();
    const int d = blockIdx.x * 128 + t;
    const float4* Wr = (const float4*)(Wd + (size_t)d * (2*DD));
    const float4* cc = (const float4*)conc;
    float acc = 0.f;
    #pragma unroll 8
    for (int k = 0; k < (2*DD)/4; ++k) {
        float4 a = Wr[k];
        float4 c = cc[k];
        acc += a.x*c.x + a.y*c.y + a.z*c.z + a.w*c.w;
    }
    w[b*DD + d] = (acc + bd[d]) * W1[d];
}

// ---------------- kernel 2: online-softmax partial over a chunk of 128 rows
// R6/R7 evidence: backend pins VGPR allocation at the 64 bucket and spills
// the RPI=4 double buffer to scratch (WRITE_SIZE 244 MB = 8 groups x 128 B
// x 262144 threads). launch_bounds(256,4) and waves_per_eu(4,4) both failed
// to raise it. Fix: make the working set FIT 64 — RPI=2 (dbuf = 32 VGPR),
// named registers (no arrays -> no SROA/scratch risk), plain launch_bounds.
// Pipeline (dbuf + sched_barrier pins) unchanged from R6, which proved the
// loads issue early (FETCH = full 253 MB stream).

#define LOADG(R00, R01, R10, R11, g)                                          \
    {   const float* p0_ = rb + (size_t)(g) * RPI * DD;                       \
        const float* p1_ = p0_ + DD;                                          \
        R00 = ((const float4*)p0_)[lane];                                     \
        R01 = ((const float4*)p0_)[64 + lane];                                \
        R10 = ((const float4*)p1_)[lane];                                     \
        R11 = ((const float4*)p1_)[64 + lane]; }

#define STEP(R00, R01, R10, R11)                                              \
    {   float d0 = R00.x*w0.x + R00.y*w0.y + R00.z*w0.z + R00.w*w0.w          \
                 + R01.x*w1.x + R01.y*w1.y + R01.z*w1.z + R01.w*w1.w;         \
        float d1 = R10.x*w0.x + R10.y*w0.y + R10.z*w0.z + R10.w*w0.w          \
                 + R11.x*w1.x + R11.y*w1.y + R11.z*w1.z + R11.w*w1.w;         \
        _Pragma("unroll")                                                     \
        for (int off = 32; off; off >>= 1) {                                  \
            d0 += __shfl_xor(d0, off, 64);                                    \
            d1 += __shfl_xor(d1, off, 64);                                    \
        }                                                                     \
        const float mn = fmaxf(fmaxf(d0, d1), m);                             \
        const float alpha = __expf(m - mn);   /* first iter: expf(-inf)=0 */  \
        m = mn;                                                               \
        const float p0 = __expf(d0 - m);                                      \
        const float p1 = __expf(d1 - m);                                      \
        l = l*alpha + p0 + p1;                                                \
        a0.x = a0.x*alpha + p0*R00.x + p1*R10.x;                              \
        a0.y = a0.y*alpha + p0*R00.y + p1*R10.y;                              \
        a0.z = a0.z*alpha + p0*R00.z + p1*R10.z;                              \
        a0.w = a0.w*alpha + p0*R00.w + p1*R10.w;                              \
        a1.x = a1.x*alpha + p0*R01.x + p1*R11.x;                              \
        a1.y = a1.y*alpha + p0*R01.y + p1*R11.y;                              \
        a1.z = a1.z*alpha + p0*R01.z + p1*R11.z;                              \
        a1.w = a1.w*alpha + p0*R01.w + p1*R11.w; }

__global__ __launch_bounds__(256) void k_pass(
    const float* __restrict__ cw, const float* __restrict__ w,
    float* __restrict__ pm, float* __restrict__ pl, float* __restrict__ pacc)
{
    const int blk  = blockIdx.x;
    const int b    = blk >> 4;        // /CH
    const int ch   = blk & (CH - 1);
    const int tid  = threadIdx.x;
    const int wave = tid >> 6;
    const int lane = tid & 63;

    // per-lane slice of w: d = 4*lane .. +3  and  256 + 4*lane .. +3
    const float4* wb = (const float4*)(w + b*DD);
    const float4 w0 = wb[lane];
    const float4 w1 = wb[64 + lane];

    // wave's contiguous 32-row strip
    const float* rb = cw + ((size_t)b*SS + (size_t)ch*ROWS + (size_t)wave*WROWS) * DD;

    // named double-buffer registers: A = group i, B = group i+1
    float4 A00, A01, A10, A11, B00, B01, B10, B11;
    LOADG(A00, A01, A10, A11, 0);

    float m = -INFINITY, l = 0.f;
    float4 a0 = make_float4(0,0,0,0), a1 = make_float4(0,0,0,0);

    for (int i = 0; i + 2 < ITERS; i += 2) {      // i = 0,2,...,ITERS-4
        LOADG(B00, B01, B10, B11, i + 1);         // prefetch group i+1
        __builtin_amdgcn_sched_barrier(0);        // pin: loads stay issued here
        STEP(A00, A01, A10, A11);                 // compute group i
        LOADG(A00, A01, A10, A11, i + 2);         // prefetch group i+2
        __builtin_amdgcn_sched_barrier(0);
        STEP(B00, B01, B10, B11);                 // compute group i+1
    }
    // tail: A holds group ITERS-2; load and process final group
    LOADG(B00, B01, B10, B11, ITERS - 1);
    __builtin_amdgcn_sched_barrier(0);
    STEP(A00, A01, A10, A11);
    STEP(B00, B01, B10, B11);

    // combine 4 waves within the block
    __shared__ float lm[4], ll[4];
    __shared__ float lacc[4][DD];
    if (lane == 0) lm[wave] = m;
    __syncthreads();
    const float M = fmaxf(fmaxf(lm[0], lm[1]), fmaxf(lm[2], lm[3]));
    const float beta = __expf(m - M);
    float4* lw = (float4*)lacc[wave];
    lw[lane]      = make_float4(a0.x*beta, a0.y*beta, a0.z*beta, a0.w*beta);
    lw[64 + lane] = make_float4(a1.x*beta, a1.y*beta, a1.z*beta, a1.w*beta);
    if (lane == 0) ll[wave] = l * beta;
    __syncthreads();
    const float s0 = lacc[0][tid]     + lacc[1][tid]     + lacc[2][tid]     + lacc[3][tid];
    const float s1 = lacc[0][tid+256] + lacc[1][tid+256] + lacc[2][tid+256] + lacc[3][tid+256];
    pacc[(size_t)blk*DD + tid]       = s0;
    pacc[(size_t)blk*DD + tid + 256] = s1;
    if (tid == 0) {
        pm[blk] = M;
        pl[blk] = ll[0] + ll[1] + ll[2] + ll[3];
    }
}

// ---------------- kernel 3: merge 16 chunk-partials per batch (float2-vectorized)
__global__ __launch_bounds__(256) void k_comb(
    const float* __restrict__ pm, const float* __restrict__ pl,
    const float* __restrict__ pacc, float* __restrict__ out)
{
    const int b = blockIdx.x;
    const int tid = threadIdx.x;
    float M = -INFINITY;
    #pragma unroll
    for (int p = 0; p < CH; ++p) M = fmaxf(M, pm[b*CH + p]);
    float L = 0.f;
    float sx = 0.f, sy = 0.f;
    #pragma unroll
    for (int p = 0; p < CH; ++p) {
        const float sc = __expf(pm[b*CH + p] - M);
        L += pl[b*CH + p] * sc;
        const float2 v = ((const float2*)(pacc + (size_t)(b*CH + p)*DD))[tid];
        sx += sc * v.x;
        sy += sc * v.y;
    }
    const float inv = 1.f / L;
    ((float2*)(out + b*DD))[tid] = make_float2(sx*inv, sy*inv);
}

extern "C" void kernel_launch(void* const* d_in, const int* in_sizes, int n_in,
                              void* d_out, int out_size, void* d_ws, size_t ws_size,
                              hipStream_t stream)
{
    const float* c1 = (const float*)d_in[0];   // c_i_1 [B,D]
    const float* q  = (const float*)d_in[1];   // q     [B,D]
    const float* cw = (const float*)d_in[2];   // cw_s  [B,S,D]
    const float* Wd = (const float*)d_in[3];   // W_d2d [D,2D]
    const float* bd = (const float*)d_in[4];   // b_d   [D]
    const float* W1 = (const float*)d_in[5];   // W_1d  [1,D]
    // d_in[6] = b_1: constant logit shift -> cancels in softmax, unused.

    float* out  = (float*)d_out;
    float* ws   = (float*)d_ws;
    float* w    = ws;                    // B*D          = 32768 floats
    float* pm   = w  + BB*DD;            // B*CH         = 1024
    float* pl   = pm + BB*CH;            // B*CH         = 1024
    float* pacc = pl + BB*CH;            // B*CH*D       = 524288

    k_w   <<<dim3(DD/128, BB), 128, 0, stream>>>(c1, q, Wd, bd, W1, w);
    k_pass<<<BB*CH,            256, 0, stream>>>(cw, w, pm, pl, pacc);
    k_comb<<<BB,               256, 0, stream>>>(pm, pl, pacc, out);
}

// Round 9
// 399.865 us; speedup vs baseline: 1.5945x; 1.0100x over previous
//
#include <hip/hip_runtime.h>
#include <math.h>

#define BB 64
#define SS 2048
#define DD 512
#define CH 32               // chunks per batch row: 2048 blocks = 8/CU = 8 waves/SIMD
#define ROWS (SS/CH)        // 64 rows per chunk
#define WROWS (ROWS/4)      // 16 rows per wave
#define RPI 2               // rows per group (dbuf fits the 64-VGPR bucket — R8-proven)
#define ITERS (WROWS/RPI)   // 8 groups per wave

// ---------------- kernel 1: w[b,d] = (concat(c1,q)[b,:] . W_d2d[d,:] + b_d[d]) * W_1d[d]
__global__ __launch_bounds__(128) void k_w(
    const float* __restrict__ c1, const float* __restrict__ q,
    const float* __restrict__ Wd, const float* __restrict__ bd,
    const float* __restrict__ W1, float* __restrict__ w)
{
    __shared__ float conc[2*DD];
    const int b = blockIdx.y;
    const int t = threadIdx.x;
    for (int i = t; i < DD; i += 128) {
        conc[i]      = c1[b*DD + i];
        conc[DD + i] = q[b*DD + i];
    }
    __syncthreads();
    const int d = blockIdx.x * 128 + t;
    const float4* Wr = (const float4*)(Wd + (size_t)d * (2*DD));
    const float4* cc = (const float4*)conc;
    float acc = 0.f;
    #pragma unroll 8
    for (int k = 0; k < (2*DD)/4; ++k) {
        float4 a = Wr[k];
        float4 c = cc[k];
        acc += a.x*c.x + a.y*c.y + a.z*c.z + a.w*c.w;
    }
    w[b*DD + d] = (acc + bd[d]) * W1[d];
}

// ---------------- kernel 2: online-softmax partial over a chunk of 64 rows
// R8 structure (named-reg double buffer, RPI=2, sched_barrier pins, no spill:
// VGPR<=64, WRITE_SIZE ~MB) — proven at k_pass~104us. Single change: CH 16->32
// doubles blocks/CU 4->8 => 8 waves/SIMD, doubling latency hiding. Each wave
// streams one 4KB group per ~900cy HBM latency; more resident waves is the
// only way to raise per-CU streaming rate in this latency-bound regime.

#define LOADG(R00, R01, R10, R11, g)                                          \
    {   const float* p0_ = rb + (size_t)(g) * RPI * DD;                       \
        const float* p1_ = p0_ + DD;                                          \
        R00 = ((const float4*)p0_)[lane];                                     \
        R01 = ((const float4*)p0_)[64 + lane];                                \
        R10 = ((const float4*)p1_)[lane];                                     \
        R11 = ((const float4*)p1_)[64 + lane]; }

#define STEP(R00, R01, R10, R11)                                              \
    {   float d0 = R00.x*w0.x + R00.y*w0.y + R00.z*w0.z + R00.w*w0.w          \
                 + R01.x*w1.x + R01.y*w1.y + R01.z*w1.z + R01.w*w1.w;         \
        float d1 = R10.x*w0.x + R10.y*w0.y + R10.z*w0.z + R10.w*w0.w          \
                 + R11.x*w1.x + R11.y*w1.y + R11.z*w1.z + R11.w*w1.w;         \
        _Pragma("unroll")                                                     \
        for (int off = 32; off; off >>= 1) {                                  \
            d0 += __shfl_xor(d0, off, 64);                                    \
            d1 += __shfl_xor(d1, off, 64);                                    \
        }                                                                     \
        const float mn = fmaxf(fmaxf(d0, d1), m);                             \
        const float alpha = __expf(m - mn);   /* first iter: expf(-inf)=0 */  \
        m = mn;                                                               \
        const float p0 = __expf(d0 - m);                                      \
        const float p1 = __expf(d1 - m);                                      \
        l = l*alpha + p0 + p1;                                                \
        a0.x = a0.x*alpha + p0*R00.x + p1*R10.x;                              \
        a0.y = a0.y*alpha + p0*R00.y + p1*R10.y;                              \
        a0.z = a0.z*alpha + p0*R00.z + p1*R10.z;                              \
        a0.w = a0.w*alpha + p0*R00.w + p1*R10.w;                              \
        a1.x = a1.x*alpha + p0*R01.x + p1*R11.x;                              \
        a1.y = a1.y*alpha + p0*R01.y + p1*R11.y;                              \
        a1.z = a1.z*alpha + p0*R01.z + p1*R11.z;                              \
        a1.w = a1.w*alpha + p0*R01.w + p1*R11.w; }

__global__ __launch_bounds__(256) void k_pass(
    const float* __restrict__ cw, const float* __restrict__ w,
    float* __restrict__ pm, float* __restrict__ pl, float* __restrict__ pacc)
{
    const int blk  = blockIdx.x;
    const int b    = blk >> 5;        // /CH
    const int ch   = blk & (CH - 1);
    const int tid  = threadIdx.x;
    const int wave = tid >> 6;
    const int lane = tid & 63;

    // per-lane slice of w: d = 4*lane .. +3  and  256 + 4*lane .. +3
    const float4* wb = (const float4*)(w + b*DD);
    const float4 w0 = wb[lane];
    const float4 w1 = wb[64 + lane];

    // wave's contiguous 16-row strip
    const float* rb = cw + ((size_t)b*SS + (size_t)ch*ROWS + (size_t)wave*WROWS) * DD;

    // named double-buffer registers: A = group i, B = group i+1
    float4 A00, A01, A10, A11, B00, B01, B10, B11;
    LOADG(A00, A01, A10, A11, 0);

    float m = -INFINITY, l = 0.f;
    float4 a0 = make_float4(0,0,0,0), a1 = make_float4(0,0,0,0);

    for (int i = 0; i + 2 < ITERS; i += 2) {      // i = 0,2,...,ITERS-4
        LOADG(B00, B01, B10, B11, i + 1);         // prefetch group i+1
        __builtin_amdgcn_sched_barrier(0);        // pin: loads stay issued here
        STEP(A00, A01, A10, A11);                 // compute group i
        LOADG(A00, A01, A10, A11, i + 2);         // prefetch group i+2
        __builtin_amdgcn_sched_barrier(0);
        STEP(B00, B01, B10, B11);                 // compute group i+1
    }
    // tail: A holds group ITERS-2; load and process final group
    LOADG(B00, B01, B10, B11, ITERS - 1);
    __builtin_amdgcn_sched_barrier(0);
    STEP(A00, A01, A10, A11);
    STEP(B00, B01, B10, B11);

    // combine 4 waves within the block
    __shared__ float lm[4], ll[4];
    __shared__ float lacc[4][DD];
    if (lane == 0) lm[wave] = m;
    __syncthreads();
    const float M = fmaxf(fmaxf(lm[0], lm[1]), fmaxf(lm[2], lm[3]));
    const float beta = __expf(m - M);
    float4* lw = (float4*)lacc[wave];
    lw[lane]      = make_float4(a0.x*beta, a0.y*beta, a0.z*beta, a0.w*beta);
    lw[64 + lane] = make_float4(a1.x*beta, a1.y*beta, a1.z*beta, a1.w*beta);
    if (lane == 0) ll[wave] = l * beta;
    __syncthreads();
    const float s0 = lacc[0][tid]     + lacc[1][tid]     + lacc[2][tid]     + lacc[3][tid];
    const float s1 = lacc[0][tid+256] + lacc[1][tid+256] + lacc[2][tid+256] + lacc[3][tid+256];
    pacc[(size_t)blk*DD + tid]       = s0;
    pacc[(size_t)blk*DD + tid + 256] = s1;
    if (tid == 0) {
        pm[blk] = M;
        pl[blk] = ll[0] + ll[1] + ll[2] + ll[3];
    }
}

// ---------------- kernel 3: merge 32 chunk-partials per batch (float2-vectorized)
__global__ __launch_bounds__(256) void k_comb(
    const float* __restrict__ pm, const float* __restrict__ pl,
    const float* __restrict__ pacc, float* __restrict__ out)
{
    const int b = blockIdx.x;
    const int tid = threadIdx.x;
    float M = -INFINITY;
    #pragma unroll
    for (int p = 0; p < CH; ++p) M = fmaxf(M, pm[b*CH + p]);
    float L = 0.f;
    float sx = 0.f, sy = 0.f;
    #pragma unroll
    for (int p = 0; p < CH; ++p) {
        const float sc = __expf(pm[b*CH + p] - M);
        L += pl[b*CH + p] * sc;
        const float2 v = ((const float2*)(pacc + (size_t)(b*CH + p)*DD))[tid];
        sx += sc * v.x;
        sy += sc * v.y;
    }
    const float inv = 1.f / L;
    ((float2*)(out + b*DD))[tid] = make_float2(sx*inv, sy*inv);
}

extern "C" void kernel_launch(void* const* d_in, const int* in_sizes, int n_in,
                              void* d_out, int out_size, void* d_ws, size_t ws_size,
                              hipStream_t stream)
{
    const float* c1 = (const float*)d_in[0];   // c_i_1 [B,D]
    const float* q  = (const float*)d_in[1];   // q     [B,D]
    const float* cw = (const float*)d_in[2];   // cw_s  [B,S,D]
    const float* Wd = (const float*)d_in[3];   // W_d2d [D,2D]
    const float* bd = (const float*)d_in[4];   // b_d   [D]
    const float* W1 = (const float*)d_in[5];   // W_1d  [1,D]
    // d_in[6] = b_1: constant logit shift -> cancels in softmax, unused.

    float* out  = (float*)d_out;
    float* ws   = (float*)d_ws;
    float* w    = ws;                    // B*D          = 32768 floats
    float* pm   = w  + BB*DD;            // B*CH         = 2048
    float* pl   = pm + BB*CH;            // B*CH         = 2048
    float* pacc = pl + BB*CH;            // B*CH*D       = 1048576 floats (4 MB)

    k_w   <<<dim3(DD/128, BB), 128, 0, stream>>>(c1, q, Wd, bd, W1, w);
    k_pass<<<BB*CH,            256, 0, stream>>>(cw, w, pm, pl, pacc);
    k_comb<<<BB,               256, 0, stream>>>(pm, pl, pacc, out);
}

// Round 10
// 378.403 us; speedup vs baseline: 1.6850x; 1.0567x over previous
//
#include <hip/hip_runtime.h>
#include <math.h>

#define BB 64
#define SS 2048
#define DD 512
#define CH 32               // 2048 blocks = 8/CU = 8 waves/SIMD (R9 config)
#define ROWS (SS/CH)        // 64 rows per chunk
#define WROWS (ROWS/4)      // 16 rows per wave
#define RPI 2               // rows per group (dbuf fits the 64-VGPR bucket — R8-proven)
#define ITERS (WROWS/RPI)   // 8 groups per wave

// ---------------- kernel 1: w[b,d] = (concat(c1,q)[b,:] . W_d2d[d,:] + b_d[d]) * W_1d[d]
__global__ __launch_bounds__(128) void k_w(
    const float* __restrict__ c1, const float* __restrict__ q,
    const float* __restrict__ Wd, const float* __restrict__ bd,
    const float* __restrict__ W1, float* __restrict__ w)
{
    __shared__ float conc[2*DD];
    const int b = blockIdx.y;
    const int t = threadIdx.x;
    for (int i = t; i < DD; i += 128) {
        conc[i]      = c1[b*DD + i];
        conc[DD + i] = q[b*DD + i];
    }
    __syncthreads();
    const int d = blockIdx.x * 128 + t;
    const float4* Wr = (const float4*)(Wd + (size_t)d * (2*DD));
    const float4* cc = (const float4*)conc;
    float acc = 0.f;
    #pragma unroll 8
    for (int k = 0; k < (2*DD)/4; ++k) {
        float4 a = Wr[k];
        float4 c = cc[k];
        acc += a.x*c.x + a.y*c.y + a.z*c.z + a.w*c.w;
    }
    w[b*DD + d] = (acc + bd[d]) * W1[d];
}

// ---------------- kernel 2: online-softmax partial over a chunk of 64 rows
// R6+R9 evidence: two different k_pass structures both pin at ~2.7 TB/s
// aggregate (10.5 GB/s/CU ~= 4 KB in flight per CU at ~900cy latency),
// invariant to 4 vs 8 waves/SIMD, VALUBusy ~3.5% -> per-CU READ-concurrency
// ceiling on the L1 path (outstanding-miss slots), not wave starvation.
// Single change vs R9: cw_s loads via __builtin_nontemporal_load
// (global_load_dwordx4 nt) — stream bypasses L1 miss tracking; data is
// touched exactly once so nt is semantically exact.

typedef float f32x4_t __attribute__((ext_vector_type(4)));

#define NTLD(DST, PTR)                                                        \
    {   f32x4_t v_ = __builtin_nontemporal_load((const f32x4_t*)(PTR));       \
        DST.x = v_.x; DST.y = v_.y; DST.z = v_.z; DST.w = v_.w; }

#define LOADG(R00, R01, R10, R11, g)                                          \
    {   const float* p0_ = rb + (size_t)(g) * RPI * DD;                       \
        const float* p1_ = p0_ + DD;                                          \
        NTLD(R00, (const float4*)p0_ + lane);                                 \
        NTLD(R01, (const float4*)p0_ + 64 + lane);                            \
        NTLD(R10, (const float4*)p1_ + lane);                                 \
        NTLD(R11, (const float4*)p1_ + 64 + lane); }

#define STEP(R00, R01, R10, R11)                                              \
    {   float d0 = R00.x*w0.x + R00.y*w0.y + R00.z*w0.z + R00.w*w0.w          \
                 + R01.x*w1.x + R01.y*w1.y + R01.z*w1.z + R01.w*w1.w;         \
        float d1 = R10.x*w0.x + R10.y*w0.y + R10.z*w0.z + R10.w*w0.w          \
                 + R11.x*w1.x + R11.y*w1.y + R11.z*w1.z + R11.w*w1.w;         \
        _Pragma("unroll")                                                     \
        for (int off = 32; off; off >>= 1) {                                  \
            d0 += __shfl_xor(d0, off, 64);                                    \
            d1 += __shfl_xor(d1, off, 64);                                    \
        }                                                                     \
        const float mn = fmaxf(fmaxf(d0, d1), m);                             \
        const float alpha = __expf(m - mn);   /* first iter: expf(-inf)=0 */  \
        m = mn;                                                               \
        const float p0 = __expf(d0 - m);                                      \
        const float p1 = __expf(d1 - m);                                      \
        l = l*alpha + p0 + p1;                                                \
        a0.x = a0.x*alpha + p0*R00.x + p1*R10.x;                              \
        a0.y = a0.y*alpha + p0*R00.y + p1*R10.y;                              \
        a0.z = a0.z*alpha + p0*R00.z + p1*R10.z;                              \
        a0.w = a0.w*alpha + p0*R00.w + p1*R10.w;                              \
        a1.x = a1.x*alpha + p0*R01.x + p1*R11.x;                              \
        a1.y = a1.y*alpha + p0*R01.y + p1*R11.y;                              \
        a1.z = a1.z*alpha + p0*R01.z + p1*R11.z;                              \
        a1.w = a1.w*alpha + p0*R01.w + p1*R11.w; }

__global__ __launch_bounds__(256) void k_pass(
    const float* __restrict__ cw, const float* __restrict__ w,
    float* __restrict__ pm, float* __restrict__ pl, float* __restrict__ pacc)
{
    const int blk  = blockIdx.x;
    const int b    = blk >> 5;        // /CH
    const int ch   = blk & (CH - 1);
    const int tid  = threadIdx.x;
    const int wave = tid >> 6;
    const int lane = tid & 63;

    // per-lane slice of w: d = 4*lane .. +3  and  256 + 4*lane .. +3
    const float4* wb = (const float4*)(w + b*DD);
    const float4 w0 = wb[lane];
    const float4 w1 = wb[64 + lane];

    // wave's contiguous 16-row strip
    const float* rb = cw + ((size_t)b*SS + (size_t)ch*ROWS + (size_t)wave*WROWS) * DD;

    // named double-buffer registers: A = group i, B = group i+1
    float4 A00, A01, A10, A11, B00, B01, B10, B11;
    LOADG(A00, A01, A10, A11, 0);

    float m = -INFINITY, l = 0.f;
    float4 a0 = make_float4(0,0,0,0), a1 = make_float4(0,0,0,0);

    for (int i = 0; i + 2 < ITERS; i += 2) {      // i = 0,2,...,ITERS-4
        LOADG(B00, B01, B10, B11, i + 1);         // prefetch group i+1
        __builtin_amdgcn_sched_barrier(0);        // pin: loads stay issued here
        STEP(A00, A01, A10, A11);                 // compute group i
        LOADG(A00, A01, A10, A11, i + 2);         // prefetch group i+2
        __builtin_amdgcn_sched_barrier(0);
        STEP(B00, B01, B10, B11);                 // compute group i+1
    }
    // tail: A holds group ITERS-2; load and process final group
    LOADG(B00, B01, B10, B11, ITERS - 1);
    __builtin_amdgcn_sched_barrier(0);
    STEP(A00, A01, A10, A11);
    STEP(B00, B01, B10, B11);

    // combine 4 waves within the block
    __shared__ float lm[4], ll[4];
    __shared__ float lacc[4][DD];
    if (lane == 0) lm[wave] = m;
    __syncthreads();
    const float M = fmaxf(fmaxf(lm[0], lm[1]), fmaxf(lm[2], lm[3]));
    const float beta = __expf(m - M);
    float4* lw = (float4*)lacc[wave];
    lw[lane]      = make_float4(a0.x*beta, a0.y*beta, a0.z*beta, a0.w*beta);
    lw[64 + lane] = make_float4(a1.x*beta, a1.y*beta, a1.z*beta, a1.w*beta);
    if (lane == 0) ll[wave] = l * beta;
    __syncthreads();
    const float s0 = lacc[0][tid]     + lacc[1][tid]     + lacc[2][tid]     + lacc[3][tid];
    const float s1 = lacc[0][tid+256] + lacc[1][tid+256] + lacc[2][tid+256] + lacc[3][tid+256];
    pacc[(size_t)blk*DD + tid]       = s0;
    pacc[(size_t)blk*DD + tid + 256] = s1;
    if (tid == 0) {
        pm[blk] = M;
        pl[blk] = ll[0] + ll[1] + ll[2] + ll[3];
    }
}

// ---------------- kernel 3: merge 32 chunk-partials per batch (float2-vectorized)
__global__ __launch_bounds__(256) void k_comb(
    const float* __restrict__ pm, const float* __restrict__ pl,
    const float* __restrict__ pacc, float* __restrict__ out)
{
    const int b = blockIdx.x;
    const int tid = threadIdx.x;
    float M = -INFINITY;
    #pragma unroll
    for (int p = 0; p < CH; ++p) M = fmaxf(M, pm[b*CH + p]);
    float L = 0.f;
    float sx = 0.f, sy = 0.f;
    #pragma unroll
    for (int p = 0; p < CH; ++p) {
        const float sc = __expf(pm[b*CH + p] - M);
        L += pl[b*CH + p] * sc;
        const float2 v = ((const float2*)(pacc + (size_t)(b*CH + p)*DD))[tid];
        sx += sc * v.x;
        sy += sc * v.y;
    }
    const float inv = 1.f / L;
    ((float2*)(out + b*DD))[tid] = make_float2(sx*inv, sy*inv);
}

extern "C" void kernel_launch(void* const* d_in, const int* in_sizes, int n_in,
                              void* d_out, int out_size, void* d_ws, size_t ws_size,
                              hipStream_t stream)
{
    const float* c1 = (const float*)d_in[0];   // c_i_1 [B,D]
    const float* q  = (const float*)d_in[1];   // q     [B,D]
    const float* cw = (const float*)d_in[2];   // cw_s  [B,S,D]
    const float* Wd = (const float*)d_in[3];   // W_d2d [D,2D]
    const float* bd = (const float*)d_in[4];   // b_d   [D]
    const float* W1 = (const float*)d_in[5];   // W_1d  [1,D]
    // d_in[6] = b_1: constant logit shift -> cancels in softmax, unused.

    float* out  = (float*)d_out;
    float* ws   = (float*)d_ws;
    float* w    = ws;                    // B*D          = 32768 floats
    float* pm   = w  + BB*DD;            // B*CH         = 2048
    float* pl   = pm + BB*CH;            // B*CH         = 2048
    float* pacc = pl + BB*CH;            // B*CH*D       = 1048576 floats (4 MB)

    k_w   <<<dim3(DD/128, BB), 128, 0, stream>>>(c1, q, Wd, bd, W1, w);
    k_pass<<<BB*CH,            256, 0, stream>>>(cw, w, pm, pl, pacc);
    k_comb<<<BB,               256, 0, stream>>>(pm, pl, pacc, out);
}